// Round 1
// baseline (1295.472 us; speedup 1.0000x reference)
//
#include <hip/hip_runtime.h>

#define VOX (128*128*32)   // 524288 voxels
#define CCH 64
#define NCL 20
#define DD 128
#define HH 128
#define WW 32
#define EPSV 1e-5f
#define THRESV 0.2f

// ---- order-preserving float <-> uint key for atomic min/max ----
__device__ __forceinline__ unsigned keyOf(float f){
    unsigned u = __float_as_uint(f);
    return (u & 0x80000000u) ? ~u : (u | 0x80000000u);
}
__device__ __forceinline__ float keyInv(unsigned k){
    unsigned u = (k & 0x80000000u) ? (k & 0x7fffffffu) : ~k;
    return __uint_as_float(u);
}

__global__ void k_init(unsigned* keys){
    int i = threadIdx.x;
    if (i < NCL){ keys[i] = 0xFFFFFFFFu; keys[NCL+i] = 0u; }
}

// ---- Pass A: logit (einsum + bias), softmax masks, per-voxel mean/max over C ----
__global__ __launch_bounds__(256) void k_logit_softmax(
    const float* __restrict__ x, const float* __restrict__ clsw,
    const float* __restrict__ clsb, float* __restrict__ masks,
    float* __restrict__ logit, float* __restrict__ mx, float* __restrict__ Mx)
{
    __shared__ float sw[NCL*CCH];
    __shared__ float sb[NCL];
    int tid = threadIdx.x;
    for (int q = tid; q < NCL*CCH; q += 256) sw[q] = clsw[q];
    if (tid < NCL) sb[tid] = clsb[tid];
    __syncthreads();
    int v = blockIdx.x*256 + tid;
    float acc[NCL];
    #pragma unroll
    for (int o=0;o<NCL;o++) acc[o] = sb[o];
    float s = 0.f, mm = -1e30f;
    for (int c=0;c<CCH;c++){
        float xv = x[c*VOX + v];
        s += xv; mm = fmaxf(mm, xv);
        #pragma unroll
        for (int o=0;o<NCL;o++) acc[o] = fmaf(xv, sw[o*CCH + c], acc[o]);
    }
    mx[v] = s * (1.f/64.f);
    Mx[v] = mm;
    float lm = acc[0];
    #pragma unroll
    for (int o=1;o<NCL;o++) lm = fmaxf(lm, acc[o]);
    float es = 0.f;
    #pragma unroll
    for (int o=0;o<NCL;o++){
        logit[o*VOX + v] = acc[o];
        float e = expf(acc[o] - lm);
        es += e; acc[o] = e;
    }
    float inv = 1.f/es;
    #pragma unroll
    for (int o=0;o<NCL;o++) masks[o*VOX + v] = acc[o]*inv;
}

// ---- Pass B: per-class 7x7x7x3 conv -> sigmoid -> ma = mask*atten; heat min/max atomics ----
// tile: 8(z) x 8(y) x 16(x) outputs, halo 3 -> LDS 14x14x22 (stride 24), 3 fields
__global__ __launch_bounds__(256) void k_conv(const float* __restrict__ masksAll,
        const float* __restrict__ mx, const float* __restrict__ Mx,
        const float* __restrict__ cfr, float* __restrict__ G,
        unsigned* __restrict__ keys)
{
    __shared__ float sf[3][14][14][24];
    __shared__ float swt[3*343];
    __shared__ float rmn[4], rmx[4];
    const int cls = blockIdx.z;
    const int zt = blockIdx.y >> 4, yt = blockIdx.y & 15;
    const int z0 = zt*8, y0 = yt*8, xw0 = blockIdx.x*16;
    const int tid = threadIdx.x;
    for (int q = tid; q < 3*343; q += 256) swt[q] = cfr[cls*1029 + q];
    const float* mk = masksAll + cls*VOX;
    for (int p = tid; p < 14*14*22; p += 256){
        int lz = p / (14*22);
        int r  = p - lz*(14*22);
        int ly = r / 22;
        int lx = r - ly*22;
        int gz = z0 + lz - 3, gy = y0 + ly - 3, gx = xw0 + lx - 3;
        float m = 0.f, a = 0.f, b = 0.f;
        if ((unsigned)gz < (unsigned)DD && (unsigned)gy < (unsigned)HH && (unsigned)gx < (unsigned)WW){
            int idx = (gz*HH + gy)*WW + gx;
            m = mk[idx]; a = mx[idx]; b = Mx[idx];
        }
        sf[0][lz][ly][lx] = m*a;   // mask * mean_c(x)
        sf[1][lz][ly][lx] = m*b;   // mask * max_c(x)
        sf[2][lz][ly][lx] = m;     // mask
    }
    __syncthreads();
    const int tz = tid >> 5;          // 0..7
    const int ty = (tid >> 2) & 7;    // 0..7
    const int xo = (tid & 3) * 4;     // 0,4,8,12
    float acc0=0.f, acc1=0.f, acc2=0.f, acc3=0.f;
    for (int t=0;t<3;t++){
        for (int dz=0;dz<7;dz++){
            #pragma unroll
            for (int dy=0;dy<7;dy++){
                const float* row = &sf[t][tz+dz][ty+dy][xo];
                float4 A  = *reinterpret_cast<const float4*>(row);
                float4 Bv = *reinterpret_cast<const float4*>(row+4);
                float2 Cv = *reinterpret_cast<const float2*>(row+8);
                float in[10] = {A.x,A.y,A.z,A.w,Bv.x,Bv.y,Bv.z,Bv.w,Cv.x,Cv.y};
                const float* wr = &swt[t*343 + dz*49 + dy*7];
                #pragma unroll
                for (int dx=0;dx<7;dx++){
                    float wv = wr[dx];
                    acc0 = fmaf(in[dx+0], wv, acc0);
                    acc1 = fmaf(in[dx+1], wv, acc1);
                    acc2 = fmaf(in[dx+2], wv, acc2);
                    acc3 = fmaf(in[dx+3], wv, acc3);
                }
            }
        }
    }
    const int gz = z0 + tz, gy = y0 + ty;
    const int base = (gz*HH + gy)*WW + xw0 + xo;
    float accv[4] = {acc0, acc1, acc2, acc3};
    float hmn = 1e30f, hmx = -1e30f;
    #pragma unroll
    for (int j=0;j<4;j++){
        float sg = 1.f/(1.f + expf(-accv[j]));
        float mv = sf[2][tz+3][ty+3][xo+3+j];
        float ma = mv * sg;
        G[cls*VOX + base + j] = ma;
        float heat = ma * mx[base + j];
        hmn = fminf(hmn, heat);
        hmx = fmaxf(hmx, heat);
    }
    #pragma unroll
    for (int off=32; off>0; off>>=1){
        hmn = fminf(hmn, __shfl_xor(hmn, off));
        hmx = fmaxf(hmx, __shfl_xor(hmx, off));
    }
    int lane = tid & 63, wid = tid >> 6;
    if (lane == 0){ rmn[wid] = hmn; rmx[wid] = hmx; }
    __syncthreads();
    if (tid == 0){
        float a = fminf(fminf(rmn[0],rmn[1]), fminf(rmn[2],rmn[3]));
        float b = fmaxf(fmaxf(rmx[0],rmx[1]), fmaxf(rmx[2],rmx[3]));
        atomicMin(&keys[cls], keyOf(a));
        atomicMax(&keys[NCL+cls], keyOf(b));
    }
}

__global__ void k_thr(const unsigned* __restrict__ keys, float* __restrict__ hminA,
                      float* __restrict__ invR){
    int i = threadIdx.x;
    if (i < NCL){
        float hm = keyInv(keys[i]);
        float hM = keyInv(keys[NCL+i]);
        hminA[i] = hm;
        invR[i] = 1.f/(hM - hm);
    }
}

// ---- g = ma * (norm > 0.2), in place ----
__global__ __launch_bounds__(256) void k_region(float* G, const float* __restrict__ mx,
        const float* __restrict__ hminA, const float* __restrict__ invR)
{
    int i = blockIdx.y;
    int v = blockIdx.x*256 + threadIdx.x;
    float ma = G[i*VOX + v];
    float heat = ma * mx[v];
    float norm = (heat - hminA[i]) * invR[i];
    G[i*VOX + v] = (norm > THRESV) ? ma : 0.f;
}

// ---- per-(class,channel) sums S1 = sum x*g, S2 = sum (x*g)^2 ----
__global__ __launch_bounds__(256) void k_stats(const float* __restrict__ x,
        const float* G, float* __restrict__ part)
{
    int tid = threadIdx.x;
    int c = tid & 63, vg = tid >> 6;
    int v0 = blockIdx.x * 2048;
    float s1[NCL], s2[NCL];
    #pragma unroll
    for (int i=0;i<NCL;i++){ s1[i]=0.f; s2[i]=0.f; }
    const float* xc = x + c*VOX;
    for (int k=0;k<512;k++){
        int v = v0 + (k<<2) + vg;   // wave-uniform v, lane = channel
        float xv = xc[v];
        #pragma unroll
        for (int i=0;i<NCL;i++){
            float p = xv * G[i*VOX + v];
            s1[i] += p;
            s2[i] = fmaf(p, p, s2[i]);
        }
    }
    __shared__ float red[4][64][2*NCL];
    #pragma unroll
    for (int i=0;i<NCL;i++){ red[vg][c][i] = s1[i]; red[vg][c][NCL+i] = s2[i]; }
    __syncthreads();
    if (vg == 0){
        float* dst = part + (size_t)blockIdx.x * (NCL*CCH*2);
        for (int i=0;i<NCL;i++){
            float a = red[0][c][i]+red[1][c][i]+red[2][c][i]+red[3][c][i];
            float b = red[0][c][NCL+i]+red[1][c][NCL+i]+red[2][c][NCL+i]+red[3][c][NCL+i];
            dst[i*CCH*2 + c*2 + 0] = a;
            dst[i*CCH*2 + c*2 + 1] = b;
        }
    }
}

// ---- finish stats: a = gamma*rinv, kc = beta - m*rinv*gamma ----
__global__ void k_params(const float* __restrict__ part, const float* __restrict__ gamma,
        const float* __restrict__ beta, float* __restrict__ aArr, float* __restrict__ kcArr)
{
    int i = blockIdx.x, c = threadIdx.x;
    float s1 = 0.f, s2 = 0.f;
    for (int b=0;b<256;b++){
        const float* p = part + (size_t)b*(NCL*CCH*2) + i*CCH*2 + c*2;
        s1 += p[0]; s2 += p[1];
    }
    float m   = s1 * (1.f/(float)VOX);
    float var = s2 * (1.f/(float)VOX) - m*m;
    float rinv = 1.f/sqrtf(var + EPSV);
    float gm = gamma[c];
    aArr[i*CCH + c]  = gm*rinv;
    kcArr[i*CCH + c] = beta[c] - m*rinv*gm;
}

__global__ void k_kcol(const float* __restrict__ kcArr, float* __restrict__ KcA){
    int c = threadIdx.x;
    if (c < CCH){
        float s = 0.f;
        for (int i=0;i<NCL;i++) s += kcArr[i*CCH + c];
        KcA[c] = s;
    }
}

// ---- final: out[c,v] = relu( x*Sum_i g_i*a_ic + K[c] ), in-place over d_out ----
__global__ __launch_bounds__(256) void k_final(const float* __restrict__ x,
        float* outAll, const float* __restrict__ aArr, const float* __restrict__ KcA)
{
    __shared__ float aL[NCL*CCH];
    __shared__ float KL[CCH];
    int tid = threadIdx.x;
    for (int q=tid; q<NCL*CCH; q+=256) aL[q] = aArr[q];
    if (tid < CCH) KL[tid] = KcA[tid];
    __syncthreads();
    int v = blockIdx.x*256 + tid;
    const float* Gp = outAll + (size_t)NCL*VOX;
    float g[NCL];
    #pragma unroll
    for (int i=0;i<NCL;i++) g[i] = Gp[i*VOX + v];   // read own column before any writes
    #pragma unroll 4
    for (int c=0;c<CCH;c++){
        float P = 0.f;
        #pragma unroll
        for (int i=0;i<NCL;i++) P = fmaf(g[i], aL[i*CCH + c], P);
        float xv = x[c*VOX + v];
        outAll[c*VOX + v] = fmaxf(0.f, fmaf(xv, P, KL[c]));
    }
}

extern "C" void kernel_launch(void* const* d_in, const int* in_sizes, int n_in,
                              void* d_out, int out_size, void* d_ws, size_t ws_size,
                              hipStream_t stream)
{
    const float* x     = (const float*)d_in[0];
    const float* clsw  = (const float*)d_in[1];
    const float* clsb  = (const float*)d_in[2];
    const float* cfr   = (const float*)d_in[3];
    const float* gamma = (const float*)d_in[4];
    const float* beta  = (const float*)d_in[5];

    float* out   = (float*)d_out;
    float* logit = out + (size_t)CCH*VOX;     // second output
    float* masks = out;                       // scratch: out[0 .. 20V)
    float* G     = out + (size_t)NCL*VOX;     // scratch: out[20V .. 40V)

    float* ws    = (float*)d_ws;
    float* mxp   = ws;                        // V
    float* Mxp   = ws + VOX;                  // V
    unsigned* keys = (unsigned*)(ws + 2*(size_t)VOX);   // 40
    float* hminA = ws + 2*(size_t)VOX + 64;   // 20
    float* invR  = hminA + NCL;               // 20
    float* part  = ws + 2*(size_t)VOX + 128;  // 256*2560
    float* aArr  = part + 256*(NCL*CCH*2);    // 1280
    float* kcArr = aArr + NCL*CCH;            // 1280
    float* KcA   = kcArr + NCL*CCH;           // 64

    k_init<<<1, 64, 0, stream>>>(keys);
    k_logit_softmax<<<VOX/256, 256, 0, stream>>>(x, clsw, clsb, masks, logit, mxp, Mxp);
    k_conv<<<dim3(2, 256, NCL), 256, 0, stream>>>(masks, mxp, Mxp, cfr, G, keys);
    k_thr<<<1, 32, 0, stream>>>(keys, hminA, invR);
    k_region<<<dim3(VOX/256, NCL), 256, 0, stream>>>(G, mxp, hminA, invR);
    k_stats<<<256, 256, 0, stream>>>(x, G, part);
    k_params<<<NCL, CCH, 0, stream>>>(part, gamma, beta, aArr, kcArr);
    k_kcol<<<1, CCH, 0, stream>>>(kcArr, KcA);
    k_final<<<VOX/256, 256, 0, stream>>>(x, out, aArr, KcA);
}

// Round 2
// 910.788 us; speedup vs baseline: 1.4224x; 1.4224x over previous
//
#include <hip/hip_runtime.h>

#define VOX (128*128*32)   // 524288 voxels
#define CCH 64
#define NCL 20
#define DD 128
#define HH 128
#define WW 32
#define ZT 16
#define EPSV 1e-5f
#define THRESV 0.2f

// ---- order-preserving float <-> uint key for atomic min/max ----
__device__ __forceinline__ unsigned keyOf(float f){
    unsigned u = __float_as_uint(f);
    return (u & 0x80000000u) ? ~u : (u | 0x80000000u);
}
__device__ __forceinline__ float keyInv(unsigned k){
    unsigned u = (k & 0x80000000u) ? (k & 0x7fffffffu) : ~k;
    return __uint_as_float(u);
}

__global__ void k_init(unsigned* keys){
    int i = threadIdx.x;
    if (i < NCL){ keys[i] = 0xFFFFFFFFu; keys[NCL+i] = 0u; }
}

// ---- Pass A: logit (einsum + bias), softmax masks, per-voxel mean/max over C ----
__global__ __launch_bounds__(256) void k_logit_softmax(
    const float* __restrict__ x, const float* __restrict__ clsw,
    const float* __restrict__ clsb, float* __restrict__ masks,
    float* __restrict__ logit, float* __restrict__ mx, float* __restrict__ Mx)
{
    __shared__ float sw[NCL*CCH];
    __shared__ float sb[NCL];
    int tid = threadIdx.x;
    for (int q = tid; q < NCL*CCH; q += 256) sw[q] = clsw[q];
    if (tid < NCL) sb[tid] = clsb[tid];
    __syncthreads();
    int v = blockIdx.x*256 + tid;
    float acc[NCL];
    #pragma unroll
    for (int o=0;o<NCL;o++) acc[o] = sb[o];
    float s = 0.f, mm = -1e30f;
    for (int c=0;c<CCH;c++){
        float xv = x[c*VOX + v];
        s += xv; mm = fmaxf(mm, xv);
        #pragma unroll
        for (int o=0;o<NCL;o++) acc[o] = fmaf(xv, sw[o*CCH + c], acc[o]);
    }
    mx[v] = s * (1.f/64.f);
    Mx[v] = mm;
    float lm = acc[0];
    #pragma unroll
    for (int o=1;o<NCL;o++) lm = fmaxf(lm, acc[o]);
    float es = 0.f;
    #pragma unroll
    for (int o=0;o<NCL;o++){
        logit[o*VOX + v] = acc[o];
        float e = expf(acc[o] - lm);
        es += e; acc[o] = e;
    }
    float inv = 1.f/es;
    #pragma unroll
    for (int o=0;o<NCL;o++) masks[o*VOX + v] = acc[o]*inv;
}

// ---- Pass B: z-marching FIR 7x7x7x3 conv -> sigmoid -> ma = mask*atten; heat min/max ----
// block = 128 threads: y = tid>>3 (16 rows), x0 = (tid&7)*4 (4 outputs in x).
// grid = (8 y-tiles, 8 z-tiles, 20 classes). LDS: one z-slice (3 fields, 22x40) + weights.
// 7 rotating float4 accumulators: at start of phase zi, aJ holds output zo = zi-3+J,
// updated this phase with kernel plane dz = 6-J; a0 completes after the phase's FMAs.

#define FMA1(AJ, WV, p,q,r,s) { AJ.x = fmaf(p, WV, AJ.x); AJ.y = fmaf(q, WV, AJ.y); \
                                AJ.z = fmaf(r, WV, AJ.z); AJ.w = fmaf(s, WV, AJ.w); }
#define DZB(AJ, WR, OFS) { \
    const float4 W0_ = *(const float4*)((WR)+(OFS)); \
    const float4 W1_ = *(const float4*)((WR)+(OFS)+4); \
    FMA1(AJ, W0_.x, i0,i1,i2,i3) \
    FMA1(AJ, W0_.y, i1,i2,i3,i4) \
    FMA1(AJ, W0_.z, i2,i3,i4,i5) \
    FMA1(AJ, W0_.w, i3,i4,i5,i6) \
    FMA1(AJ, W1_.x, i4,i5,i6,i7) \
    FMA1(AJ, W1_.y, i5,i6,i7,i8) \
    FMA1(AJ, W1_.z, i6,i7,i8,i9) }

__global__ __launch_bounds__(128) void k_conv2(const float* __restrict__ masksAll,
        const float* __restrict__ mxp, const float* __restrict__ Mxp,
        const float* __restrict__ cfr, float* __restrict__ G,
        unsigned* __restrict__ keys)
{
    __shared__ __align__(16) float FL[3][22][40];   // fields: m*mx, m*Mx, m
    __shared__ __align__(16) float WL[1176];        // weights, rows padded to 8
    __shared__ float r4[4];
    const int cls = blockIdx.z;
    const int y0 = blockIdx.x * 16;
    const int z0 = blockIdx.y * ZT;
    const int tid = threadIdx.x;
    const int y  = tid >> 3;
    const int x0 = (tid & 7) * 4;
    const float* mk = masksAll + (size_t)cls * VOX;

    for (int q = tid; q < 1176; q += 128){
        int col = q & 7, row = q >> 3;
        WL[q] = (col < 7) ? cfr[cls*1029 + row*7 + col] : 0.f;
    }
    float* FLf = &FL[0][0][0];
    for (int q = tid; q < 2640; q += 128) FLf[q] = 0.f;

    float4 a0{},a1{},a2{},a3{},a4{},a5{},a6{};
    float hmn = 1e30f, hmx = -1e30f;

    for (int zi = z0 - 3; zi <= z0 + ZT + 2; ++zi){
        __syncthreads();
        // stage slice zi (invalid (gy,gx) positions stay pre-zeroed)
        {
            const bool zok = (unsigned)zi < (unsigned)DD;
            #pragma unroll
            for (int it = 0; it < 7; ++it){
                int p = tid + it*128;
                if (p < 880){
                    int ly = p / 40;
                    int lx = p - ly*40;
                    int gy = y0 + ly - 3;
                    int gx = lx - 3;
                    if ((unsigned)gy < (unsigned)HH && (unsigned)gx < (unsigned)WW){
                        float m = 0.f, aa = 0.f, bb = 0.f;
                        if (zok){
                            int idx = (zi*HH + gy)*WW + gx;
                            m = mk[idx]; aa = mxp[idx]; bb = Mxp[idx];
                        }
                        FL[0][ly][lx] = m*aa;
                        FL[1][ly][lx] = m*bb;
                        FL[2][ly][lx] = m;
                    }
                }
            }
        }
        __syncthreads();

        const int zo = zi - 3;
        const bool fin = (zi >= z0 + 3);            // zo in [z0, z0+ZT) (upper bound implied by loop)
        float4 mv4{}, mxv4{};
        int oidx = 0;
        if (fin){                                    // prefetch finalize operands early
            oidx = (zo*HH + (y0 + y))*WW + x0;
            mv4  = *(const float4*)(mk  + oidx);
            mxv4 = *(const float4*)(mxp + oidx);
        }
        const int lo = z0 + 3 - zi;                  // okJ: J>=lo && J-lo<ZT (wave-uniform)
        const bool ok0 = (0>=lo) && (0-lo<ZT);
        const bool ok1 = (1>=lo) && (1-lo<ZT);
        const bool ok2 = (2>=lo) && (2-lo<ZT);
        const bool ok3 = (3>=lo) && (3-lo<ZT);
        const bool ok4 = (4>=lo) && (4-lo<ZT);
        const bool ok5 = (5>=lo) && (5-lo<ZT);
        const bool ok6 = (6>=lo) && (6-lo<ZT);

        #pragma unroll
        for (int t = 0; t < 3; ++t){
            const float* fb = &FL[t][y][x0];
            const float* wb = &WL[t*392];
            #pragma unroll 1
            for (int dy = 0; dy < 7; ++dy){
                const float* fr = fb + dy*40;
                const float4 A  = *(const float4*)(fr);
                const float4 Bv = *(const float4*)(fr + 4);
                const float2 Cv = *(const float2*)(fr + 8);
                const float i0=A.x,  i1=A.y,  i2=A.z,  i3=A.w;
                const float i4=Bv.x, i5=Bv.y, i6=Bv.z, i7=Bv.w;
                const float i8=Cv.x, i9=Cv.y;
                const float* wr = wb + dy*8;
                if (ok6) DZB(a6, wr, 0)      // dz = 0
                if (ok5) DZB(a5, wr, 56)     // dz = 1
                if (ok4) DZB(a4, wr, 112)    // dz = 2
                if (ok3) DZB(a3, wr, 168)    // dz = 3
                if (ok2) DZB(a2, wr, 224)    // dz = 4
                if (ok1) DZB(a1, wr, 280)    // dz = 5
                if (ok0) DZB(a0, wr, 336)    // dz = 6
            }
        }

        if (fin){
            float s0 = 1.f/(1.f + expf(-a0.x));
            float s1 = 1.f/(1.f + expf(-a0.y));
            float s2 = 1.f/(1.f + expf(-a0.z));
            float s3 = 1.f/(1.f + expf(-a0.w));
            float4 res;
            res.x = mv4.x*s0; res.y = mv4.y*s1; res.z = mv4.z*s2; res.w = mv4.w*s3;
            *(float4*)(G + (size_t)cls*VOX + oidx) = res;
            float h0 = res.x*mxv4.x, h1 = res.y*mxv4.y;
            float h2 = res.z*mxv4.z, h3 = res.w*mxv4.w;
            hmn = fminf(hmn, fminf(fminf(h0,h1), fminf(h2,h3)));
            hmx = fmaxf(hmx, fmaxf(fmaxf(h0,h1), fmaxf(h2,h3)));
        }
        a0=a1; a1=a2; a2=a3; a3=a4; a4=a5; a5=a6;
        a6 = make_float4(0.f,0.f,0.f,0.f);
    }

    #pragma unroll
    for (int off = 32; off > 0; off >>= 1){
        hmn = fminf(hmn, __shfl_xor(hmn, off));
        hmx = fmaxf(hmx, __shfl_xor(hmx, off));
    }
    if ((tid & 63) == 0){ r4[(tid>>6)*2] = hmn; r4[(tid>>6)*2+1] = hmx; }
    __syncthreads();
    if (tid == 0){
        atomicMin(&keys[cls],     keyOf(fminf(r4[0], r4[2])));
        atomicMax(&keys[NCL+cls], keyOf(fmaxf(r4[1], r4[3])));
    }
}

__global__ void k_thr(const unsigned* __restrict__ keys, float* __restrict__ hminA,
                      float* __restrict__ invR){
    int i = threadIdx.x;
    if (i < NCL){
        float hm = keyInv(keys[i]);
        float hM = keyInv(keys[NCL+i]);
        hminA[i] = hm;
        invR[i] = 1.f/(hM - hm);
    }
}

// ---- g = ma * (norm > 0.2), in place ----
__global__ __launch_bounds__(256) void k_region(float* G, const float* __restrict__ mx,
        const float* __restrict__ hminA, const float* __restrict__ invR)
{
    int i = blockIdx.y;
    int v = blockIdx.x*256 + threadIdx.x;
    float ma = G[i*VOX + v];
    float heat = ma * mx[v];
    float norm = (heat - hminA[i]) * invR[i];
    G[i*VOX + v] = (norm > THRESV) ? ma : 0.f;
}

// ---- per-(class,channel) sums S1 = sum x*g, S2 = sum (x*g)^2 ----
__global__ __launch_bounds__(256) void k_stats(const float* __restrict__ x,
        const float* G, float* __restrict__ part)
{
    int tid = threadIdx.x;
    int c = tid & 63, vg = tid >> 6;
    int v0 = blockIdx.x * 2048;
    float s1[NCL], s2[NCL];
    #pragma unroll
    for (int i=0;i<NCL;i++){ s1[i]=0.f; s2[i]=0.f; }
    const float* xc = x + c*VOX;
    for (int k=0;k<512;k++){
        int v = v0 + (k<<2) + vg;
        float xv = xc[v];
        #pragma unroll
        for (int i=0;i<NCL;i++){
            float p = xv * G[i*VOX + v];
            s1[i] += p;
            s2[i] = fmaf(p, p, s2[i]);
        }
    }
    __shared__ float red[4][64][2*NCL];
    #pragma unroll
    for (int i=0;i<NCL;i++){ red[vg][c][i] = s1[i]; red[vg][c][NCL+i] = s2[i]; }
    __syncthreads();
    if (vg == 0){
        float* dst = part + (size_t)blockIdx.x * (NCL*CCH*2);
        for (int i=0;i<NCL;i++){
            float a = red[0][c][i]+red[1][c][i]+red[2][c][i]+red[3][c][i];
            float b = red[0][c][NCL+i]+red[1][c][NCL+i]+red[2][c][NCL+i]+red[3][c][NCL+i];
            dst[i*CCH*2 + c*2 + 0] = a;
            dst[i*CCH*2 + c*2 + 1] = b;
        }
    }
}

// ---- finish stats: a = gamma*rinv, kc = beta - m*rinv*gamma ----
__global__ void k_params(const float* __restrict__ part, const float* __restrict__ gamma,
        const float* __restrict__ beta, float* __restrict__ aArr, float* __restrict__ kcArr)
{
    int i = blockIdx.x, c = threadIdx.x;
    float s1 = 0.f, s2 = 0.f;
    for (int b=0;b<256;b++){
        const float* p = part + (size_t)b*(NCL*CCH*2) + i*CCH*2 + c*2;
        s1 += p[0]; s2 += p[1];
    }
    float m   = s1 * (1.f/(float)VOX);
    float var = s2 * (1.f/(float)VOX) - m*m;
    float rinv = 1.f/sqrtf(var + EPSV);
    float gm = gamma[c];
    aArr[i*CCH + c]  = gm*rinv;
    kcArr[i*CCH + c] = beta[c] - m*rinv*gm;
}

__global__ void k_kcol(const float* __restrict__ kcArr, float* __restrict__ KcA){
    int c = threadIdx.x;
    if (c < CCH){
        float s = 0.f;
        for (int i=0;i<NCL;i++) s += kcArr[i*CCH + c];
        KcA[c] = s;
    }
}

// ---- final: out[c,v] = relu( x*Sum_i g_i*a_ic + K[c] ), in-place over d_out ----
__global__ __launch_bounds__(256) void k_final(const float* __restrict__ x,
        float* outAll, const float* __restrict__ aArr, const float* __restrict__ KcA)
{
    __shared__ float aL[NCL*CCH];
    __shared__ float KL[CCH];
    int tid = threadIdx.x;
    for (int q=tid; q<NCL*CCH; q+=256) aL[q] = aArr[q];
    if (tid < CCH) KL[tid] = KcA[tid];
    __syncthreads();
    int v = blockIdx.x*256 + tid;
    const float* Gp = outAll + (size_t)NCL*VOX;
    float g[NCL];
    #pragma unroll
    for (int i=0;i<NCL;i++) g[i] = Gp[i*VOX + v];
    #pragma unroll 4
    for (int c=0;c<CCH;c++){
        float P = 0.f;
        #pragma unroll
        for (int i=0;i<NCL;i++) P = fmaf(g[i], aL[i*CCH + c], P);
        float xv = x[c*VOX + v];
        outAll[c*VOX + v] = fmaxf(0.f, fmaf(xv, P, KL[c]));
    }
}

extern "C" void kernel_launch(void* const* d_in, const int* in_sizes, int n_in,
                              void* d_out, int out_size, void* d_ws, size_t ws_size,
                              hipStream_t stream)
{
    const float* x     = (const float*)d_in[0];
    const float* clsw  = (const float*)d_in[1];
    const float* clsb  = (const float*)d_in[2];
    const float* cfr   = (const float*)d_in[3];
    const float* gamma = (const float*)d_in[4];
    const float* beta  = (const float*)d_in[5];

    float* out   = (float*)d_out;
    float* logit = out + (size_t)CCH*VOX;     // second output
    float* masks = out;                       // scratch: out[0 .. 20V)
    float* G     = out + (size_t)NCL*VOX;     // scratch: out[20V .. 40V)

    float* ws    = (float*)d_ws;
    float* mxp   = ws;                        // V
    float* Mxp   = ws + VOX;                  // V
    unsigned* keys = (unsigned*)(ws + 2*(size_t)VOX);   // 40
    float* hminA = ws + 2*(size_t)VOX + 64;   // 20
    float* invR  = hminA + NCL;               // 20
    float* part  = ws + 2*(size_t)VOX + 128;  // 256*2560
    float* aArr  = part + 256*(NCL*CCH*2);    // 1280
    float* kcArr = aArr + NCL*CCH;            // 1280
    float* KcA   = kcArr + NCL*CCH;           // 64

    k_init<<<1, 64, 0, stream>>>(keys);
    k_logit_softmax<<<VOX/256, 256, 0, stream>>>(x, clsw, clsb, masks, logit, mxp, Mxp);
    k_conv2<<<dim3(8, 8, NCL), 128, 0, stream>>>(masks, mxp, Mxp, cfr, G, keys);
    k_thr<<<1, 32, 0, stream>>>(keys, hminA, invR);
    k_region<<<dim3(VOX/256, NCL), 256, 0, stream>>>(G, mxp, hminA, invR);
    k_stats<<<256, 256, 0, stream>>>(x, G, part);
    k_params<<<NCL, CCH, 0, stream>>>(part, gamma, beta, aArr, kcArr);
    k_kcol<<<1, CCH, 0, stream>>>(kcArr, KcA);
    k_final<<<VOX/256, 256, 0, stream>>>(x, out, aArr, KcA);
}

// Round 3
// 873.361 us; speedup vs baseline: 1.4833x; 1.0429x over previous
//
#include <hip/hip_runtime.h>

#define VOX (128*128*32)   // 524288 voxels
#define CCH 64
#define NCL 20
#define DD 128
#define HH 128
#define WW 32
#define ZT 8
#define EPSV 1e-5f
#define THRESV 0.2f

// ---- order-preserving float <-> uint key for atomic min/max ----
__device__ __forceinline__ unsigned keyOf(float f){
    unsigned u = __float_as_uint(f);
    return (u & 0x80000000u) ? ~u : (u | 0x80000000u);
}
__device__ __forceinline__ float keyInv(unsigned k){
    unsigned u = (k & 0x80000000u) ? (k & 0x7fffffffu) : ~k;
    return __uint_as_float(u);
}

__global__ void k_init(unsigned* keys){
    int i = threadIdx.x;
    if (i < NCL){ keys[i] = 0xFFFFFFFFu; keys[NCL+i] = 0u; }
}

// ---- Pass A: logit (einsum + bias), softmax masks, per-voxel mean/max over C ----
__global__ __launch_bounds__(256) void k_logit_softmax(
    const float* __restrict__ x, const float* __restrict__ clsw,
    const float* __restrict__ clsb, float* __restrict__ masks,
    float* __restrict__ logit, float* __restrict__ mx, float* __restrict__ Mx)
{
    __shared__ float sw[NCL*CCH];
    __shared__ float sb[NCL];
    int tid = threadIdx.x;
    for (int q = tid; q < NCL*CCH; q += 256) sw[q] = clsw[q];
    if (tid < NCL) sb[tid] = clsb[tid];
    __syncthreads();
    int v = blockIdx.x*256 + tid;
    float acc[NCL];
    #pragma unroll
    for (int o=0;o<NCL;o++) acc[o] = sb[o];
    float s = 0.f, mm = -1e30f;
    for (int c=0;c<CCH;c++){
        float xv = x[c*VOX + v];
        s += xv; mm = fmaxf(mm, xv);
        #pragma unroll
        for (int o=0;o<NCL;o++) acc[o] = fmaf(xv, sw[o*CCH + c], acc[o]);
    }
    mx[v] = s * (1.f/64.f);
    Mx[v] = mm;
    float lm = acc[0];
    #pragma unroll
    for (int o=1;o<NCL;o++) lm = fmaxf(lm, acc[o]);
    float es = 0.f;
    #pragma unroll
    for (int o=0;o<NCL;o++){
        logit[o*VOX + v] = acc[o];
        float e = expf(acc[o] - lm);
        es += e; acc[o] = e;
    }
    float inv = 1.f/es;
    #pragma unroll
    for (int o=0;o<NCL;o++) masks[o*VOX + v] = acc[o]*inv;
}

// ---- Pass B: z-marching FIR 7x7x7x3 conv -> sigmoid -> ma = mask*atten; heat min/max ----
// block = 128 threads: y = tid>>3 (16 rows), x0 = (tid&7)*4 (4 outputs in x).
// grid = (8 y-tiles, 16 z-tiles, 20 classes) = 2560 blocks = 10/CU exactly.
// 7 rotating float4 accumulators: at start of phase zi, aJ holds output zo = zi-3+J,
// updated this phase with kernel plane dz = 6-J; a0 completes after the phase's FMAs.

#define FMA1(AJ, WV, p,q,r,s) { AJ.x = fmaf(p, WV, AJ.x); AJ.y = fmaf(q, WV, AJ.y); \
                                AJ.z = fmaf(r, WV, AJ.z); AJ.w = fmaf(s, WV, AJ.w); }
#define DZB(AJ, WR, OFS) { \
    const float4 W0_ = *(const float4*)((WR)+(OFS)); \
    const float4 W1_ = *(const float4*)((WR)+(OFS)+4); \
    FMA1(AJ, W0_.x, i0,i1,i2,i3) \
    FMA1(AJ, W0_.y, i1,i2,i3,i4) \
    FMA1(AJ, W0_.z, i2,i3,i4,i5) \
    FMA1(AJ, W0_.w, i3,i4,i5,i6) \
    FMA1(AJ, W1_.x, i4,i5,i6,i7) \
    FMA1(AJ, W1_.y, i5,i6,i7,i8) \
    FMA1(AJ, W1_.z, i6,i7,i8,i9) }

__global__ __launch_bounds__(128) void k_conv3(const float* __restrict__ masksAll,
        const float* __restrict__ mxp, const float* __restrict__ Mxp,
        const float* __restrict__ cfr, float* __restrict__ G,
        unsigned* __restrict__ keys)
{
    __shared__ __align__(16) float FL[3][22][40];   // fields: m*mx, m*Mx, m
    __shared__ __align__(16) float WL[1176];        // weights, rows padded to 8
    __shared__ float r4[4];
    const int cls = blockIdx.z;
    const int y0 = blockIdx.x * 16;
    const int z0 = blockIdx.y * ZT;
    const int tid = threadIdx.x;
    const int y  = tid >> 3;
    const int x0 = (tid & 7) * 4;
    const float* mk = masksAll + (size_t)cls * VOX;

    for (int q = tid; q < 1176; q += 128){
        int col = q & 7, row = q >> 3;
        WL[q] = (col < 7) ? cfr[cls*1029 + row*7 + col] : 0.f;
    }
    float* FLf = &FL[0][0][0];
    for (int q = tid; q < 2640; q += 128) FLf[q] = 0.f;

    float4 a0{},a1{},a2{},a3{},a4{},a5{},a6{};
    float hmn = 1e30f, hmx = -1e30f;

    for (int zi = z0 - 3; zi <= z0 + ZT + 2; ++zi){
        __syncthreads();
        // stage slice zi (invalid (gy,gx) positions stay pre-zeroed)
        {
            const bool zok = (unsigned)zi < (unsigned)DD;
            #pragma unroll
            for (int it = 0; it < 7; ++it){
                int p = tid + it*128;
                if (p < 880){
                    int ly = p / 40;
                    int lx = p - ly*40;
                    int gy = y0 + ly - 3;
                    int gx = lx - 3;
                    if ((unsigned)gy < (unsigned)HH && (unsigned)gx < (unsigned)WW){
                        float m = 0.f, aa = 0.f, bb = 0.f;
                        if (zok){
                            int idx = (zi*HH + gy)*WW + gx;
                            m = mk[idx]; aa = mxp[idx]; bb = Mxp[idx];
                        }
                        FL[0][ly][lx] = m*aa;
                        FL[1][ly][lx] = m*bb;
                        FL[2][ly][lx] = m;
                    }
                }
            }
        }
        __syncthreads();

        const int zo = zi - 3;
        const bool fin = (zi >= z0 + 3);            // zo in [z0, z0+ZT) (upper bound implied by loop)
        float4 mv4{}, mxv4{};
        int oidx = 0;
        if (fin){                                    // prefetch finalize operands early
            oidx = (zo*HH + (y0 + y))*WW + x0;
            mv4  = *(const float4*)(mk  + oidx);
            mxv4 = *(const float4*)(mxp + oidx);
        }
        const int lo = z0 + 3 - zi;                  // okJ: J>=lo && J-lo<ZT (wave-uniform)
        const bool ok0 = (0>=lo) && (0-lo<ZT);
        const bool ok1 = (1>=lo) && (1-lo<ZT);
        const bool ok2 = (2>=lo) && (2-lo<ZT);
        const bool ok3 = (3>=lo) && (3-lo<ZT);
        const bool ok4 = (4>=lo) && (4-lo<ZT);
        const bool ok5 = (5>=lo) && (5-lo<ZT);
        const bool ok6 = (6>=lo) && (6-lo<ZT);

        #pragma unroll
        for (int t = 0; t < 3; ++t){
            const float* fb = &FL[t][y][x0];
            const float* wb = &WL[t*392];
            #pragma unroll 1
            for (int dy = 0; dy < 7; ++dy){
                const float* fr = fb + dy*40;
                const float4 A  = *(const float4*)(fr);
                const float4 Bv = *(const float4*)(fr + 4);
                const float4 Cv = *(const float4*)(fr + 8);
                const float i0=A.x,  i1=A.y,  i2=A.z,  i3=A.w;
                const float i4=Bv.x, i5=Bv.y, i6=Bv.z, i7=Bv.w;
                const float i8=Cv.x, i9=Cv.y;
                const float* wr = wb + dy*8;
                if (ok6) DZB(a6, wr, 0)      // dz = 0
                if (ok5) DZB(a5, wr, 56)     // dz = 1
                if (ok4) DZB(a4, wr, 112)    // dz = 2
                if (ok3) DZB(a3, wr, 168)    // dz = 3
                if (ok2) DZB(a2, wr, 224)    // dz = 4
                if (ok1) DZB(a1, wr, 280)    // dz = 5
                if (ok0) DZB(a0, wr, 336)    // dz = 6
            }
        }

        if (fin){
            float s0 = 1.f/(1.f + expf(-a0.x));
            float s1 = 1.f/(1.f + expf(-a0.y));
            float s2 = 1.f/(1.f + expf(-a0.z));
            float s3 = 1.f/(1.f + expf(-a0.w));
            float4 res;
            res.x = mv4.x*s0; res.y = mv4.y*s1; res.z = mv4.z*s2; res.w = mv4.w*s3;
            *(float4*)(G + (size_t)cls*VOX + oidx) = res;
            float h0 = res.x*mxv4.x, h1 = res.y*mxv4.y;
            float h2 = res.z*mxv4.z, h3 = res.w*mxv4.w;
            hmn = fminf(hmn, fminf(fminf(h0,h1), fminf(h2,h3)));
            hmx = fmaxf(hmx, fmaxf(fmaxf(h0,h1), fmaxf(h2,h3)));
        }
        a0=a1; a1=a2; a2=a3; a3=a4; a4=a5; a5=a6;
        a6 = make_float4(0.f,0.f,0.f,0.f);
    }

    #pragma unroll
    for (int off = 32; off > 0; off >>= 1){
        hmn = fminf(hmn, __shfl_xor(hmn, off));
        hmx = fmaxf(hmx, __shfl_xor(hmx, off));
    }
    if ((tid & 63) == 0){ r4[(tid>>6)*2] = hmn; r4[(tid>>6)*2+1] = hmx; }
    __syncthreads();
    if (tid == 0){
        atomicMin(&keys[cls],     keyOf(fminf(r4[0], r4[2])));
        atomicMax(&keys[NCL+cls], keyOf(fmaxf(r4[1], r4[3])));
    }
}

__global__ void k_thr(const unsigned* __restrict__ keys, float* __restrict__ hminA,
                      float* __restrict__ invR){
    int i = threadIdx.x;
    if (i < NCL){
        float hm = keyInv(keys[i]);
        float hM = keyInv(keys[NCL+i]);
        hminA[i] = hm;
        invR[i] = 1.f/(hM - hm);
    }
}

// ---- g = ma * (norm > 0.2), in place ----
__global__ __launch_bounds__(256) void k_region(float* G, const float* __restrict__ mx,
        const float* __restrict__ hminA, const float* __restrict__ invR)
{
    int i = blockIdx.y;
    int v = blockIdx.x*256 + threadIdx.x;
    float ma = G[i*VOX + v];
    float heat = ma * mx[v];
    float norm = (heat - hminA[i]) * invR[i];
    G[i*VOX + v] = (norm > THRESV) ? ma : 0.f;
}

// ---- per-(class,channel) sums S1 = sum x*g, S2 = sum (x*g)^2 ----
__global__ __launch_bounds__(256) void k_stats(const float* __restrict__ x,
        const float* G, float* __restrict__ part)
{
    int tid = threadIdx.x;
    int c = tid & 63, vg = tid >> 6;
    int v0 = blockIdx.x * 2048;
    float s1[NCL], s2[NCL];
    #pragma unroll
    for (int i=0;i<NCL;i++){ s1[i]=0.f; s2[i]=0.f; }
    const float* xc = x + c*VOX;
    for (int k=0;k<512;k++){
        int v = v0 + (k<<2) + vg;
        float xv = xc[v];
        #pragma unroll
        for (int i=0;i<NCL;i++){
            float p = xv * G[i*VOX + v];
            s1[i] += p;
            s2[i] = fmaf(p, p, s2[i]);
        }
    }
    __shared__ float red[4][64][2*NCL];
    #pragma unroll
    for (int i=0;i<NCL;i++){ red[vg][c][i] = s1[i]; red[vg][c][NCL+i] = s2[i]; }
    __syncthreads();
    if (vg == 0){
        float* dst = part + (size_t)blockIdx.x * (NCL*CCH*2);
        for (int i=0;i<NCL;i++){
            float a = red[0][c][i]+red[1][c][i]+red[2][c][i]+red[3][c][i];
            float b = red[0][c][NCL+i]+red[1][c][NCL+i]+red[2][c][NCL+i]+red[3][c][NCL+i];
            dst[i*CCH*2 + c*2 + 0] = a;
            dst[i*CCH*2 + c*2 + 1] = b;
        }
    }
}

// ---- finish stats: a = gamma*rinv, kc = beta - m*rinv*gamma ----
__global__ void k_params(const float* __restrict__ part, const float* __restrict__ gamma,
        const float* __restrict__ beta, float* __restrict__ aArr, float* __restrict__ kcArr)
{
    int i = blockIdx.x, c = threadIdx.x;
    float s1 = 0.f, s2 = 0.f;
    for (int b=0;b<256;b++){
        const float* p = part + (size_t)b*(NCL*CCH*2) + i*CCH*2 + c*2;
        s1 += p[0]; s2 += p[1];
    }
    float m   = s1 * (1.f/(float)VOX);
    float var = s2 * (1.f/(float)VOX) - m*m;
    float rinv = 1.f/sqrtf(var + EPSV);
    float gm = gamma[c];
    aArr[i*CCH + c]  = gm*rinv;
    kcArr[i*CCH + c] = beta[c] - m*rinv*gm;
}

__global__ void k_kcol(const float* __restrict__ kcArr, float* __restrict__ KcA){
    int c = threadIdx.x;
    if (c < CCH){
        float s = 0.f;
        for (int i=0;i<NCL;i++) s += kcArr[i*CCH + c];
        KcA[c] = s;
    }
}

// ---- final: out[c,v] = relu( x*Sum_i g_i*a_ic + K[c] ), in-place over d_out ----
__global__ __launch_bounds__(256) void k_final(const float* __restrict__ x,
        float* outAll, const float* __restrict__ aArr, const float* __restrict__ KcA)
{
    __shared__ float aL[NCL*CCH];
    __shared__ float KL[CCH];
    int tid = threadIdx.x;
    for (int q=tid; q<NCL*CCH; q+=256) aL[q] = aArr[q];
    if (tid < CCH) KL[tid] = KcA[tid];
    __syncthreads();
    int v = blockIdx.x*256 + tid;
    const float* Gp = outAll + (size_t)NCL*VOX;
    float g[NCL];
    #pragma unroll
    for (int i=0;i<NCL;i++) g[i] = Gp[i*VOX + v];
    #pragma unroll 4
    for (int c=0;c<CCH;c++){
        float P = 0.f;
        #pragma unroll
        for (int i=0;i<NCL;i++) P = fmaf(g[i], aL[i*CCH + c], P);
        float xv = x[c*VOX + v];
        outAll[c*VOX + v] = fmaxf(0.f, fmaf(xv, P, KL[c]));
    }
}

extern "C" void kernel_launch(void* const* d_in, const int* in_sizes, int n_in,
                              void* d_out, int out_size, void* d_ws, size_t ws_size,
                              hipStream_t stream)
{
    const float* x     = (const float*)d_in[0];
    const float* clsw  = (const float*)d_in[1];
    const float* clsb  = (const float*)d_in[2];
    const float* cfr   = (const float*)d_in[3];
    const float* gamma = (const float*)d_in[4];
    const float* beta  = (const float*)d_in[5];

    float* out   = (float*)d_out;
    float* logit = out + (size_t)CCH*VOX;     // second output
    float* masks = out;                       // scratch: out[0 .. 20V)
    float* G     = out + (size_t)NCL*VOX;     // scratch: out[20V .. 40V)

    float* ws    = (float*)d_ws;
    float* mxp   = ws;                        // V
    float* Mxp   = ws + VOX;                  // V
    unsigned* keys = (unsigned*)(ws + 2*(size_t)VOX);   // 40
    float* hminA = ws + 2*(size_t)VOX + 64;   // 20
    float* invR  = hminA + NCL;               // 20
    float* part  = ws + 2*(size_t)VOX + 128;  // 256*2560
    float* aArr  = part + 256*(NCL*CCH*2);    // 1280
    float* kcArr = aArr + NCL*CCH;            // 1280
    float* KcA   = kcArr + NCL*CCH;           // 64

    k_init<<<1, 64, 0, stream>>>(keys);
    k_logit_softmax<<<VOX/256, 256, 0, stream>>>(x, clsw, clsb, masks, logit, mxp, Mxp);
    k_conv3<<<dim3(8, 16, NCL), 128, 0, stream>>>(masks, mxp, Mxp, cfr, G, keys);
    k_thr<<<1, 32, 0, stream>>>(keys, hminA, invR);
    k_region<<<dim3(VOX/256, NCL), 256, 0, stream>>>(G, mxp, hminA, invR);
    k_stats<<<256, 256, 0, stream>>>(x, G, part);
    k_params<<<NCL, CCH, 0, stream>>>(part, gamma, beta, aArr, kcArr);
    k_kcol<<<1, CCH, 0, stream>>>(kcArr, KcA);
    k_final<<<VOX/256, 256, 0, stream>>>(x, out, aArr, KcA);
}

// Round 4
// 810.753 us; speedup vs baseline: 1.5979x; 1.0772x over previous
//
#include <hip/hip_runtime.h>

#define VOX (128*128*32)   // 524288 voxels
#define CCH 64
#define NCL 20
#define DD 128
#define HH 128
#define WW 32
#define ZT 8
#define EPSV 1e-5f
#define THRESV 0.2f

// ---- order-preserving float <-> uint key for atomic min/max ----
__device__ __forceinline__ unsigned keyOf(float f){
    unsigned u = __float_as_uint(f);
    return (u & 0x80000000u) ? ~u : (u | 0x80000000u);
}
__device__ __forceinline__ float keyInv(unsigned k){
    unsigned u = (k & 0x80000000u) ? (k & 0x7fffffffu) : ~k;
    return __uint_as_float(u);
}

__global__ void k_init(unsigned* keys){
    int i = threadIdx.x;
    if (i < NCL){ keys[i] = 0xFFFFFFFFu; keys[NCL+i] = 0u; }
}

// ---- Pass A: logit (einsum + bias), softmax masks, per-voxel mean/max over C ----
__global__ __launch_bounds__(256) void k_logit_softmax(
    const float* __restrict__ x, const float* __restrict__ clsw,
    const float* __restrict__ clsb, float* __restrict__ masks,
    float* __restrict__ logit, float* __restrict__ mx, float* __restrict__ Mx)
{
    __shared__ float sw[NCL*CCH];
    __shared__ float sb[NCL];
    int tid = threadIdx.x;
    for (int q = tid; q < NCL*CCH; q += 256) sw[q] = clsw[q];
    if (tid < NCL) sb[tid] = clsb[tid];
    __syncthreads();
    int v = blockIdx.x*256 + tid;
    float acc[NCL];
    #pragma unroll
    for (int o=0;o<NCL;o++) acc[o] = sb[o];
    float s = 0.f, mm = -1e30f;
    for (int c=0;c<CCH;c++){
        float xv = x[c*VOX + v];
        s += xv; mm = fmaxf(mm, xv);
        #pragma unroll
        for (int o=0;o<NCL;o++) acc[o] = fmaf(xv, sw[o*CCH + c], acc[o]);
    }
    mx[v] = s * (1.f/64.f);
    Mx[v] = mm;
    float lm = acc[0];
    #pragma unroll
    for (int o=1;o<NCL;o++) lm = fmaxf(lm, acc[o]);
    float es = 0.f;
    #pragma unroll
    for (int o=0;o<NCL;o++){
        logit[o*VOX + v] = acc[o];
        float e = expf(acc[o] - lm);
        es += e; acc[o] = e;
    }
    float inv = 1.f/es;
    #pragma unroll
    for (int o=0;o<NCL;o++) masks[o*VOX + v] = acc[o]*inv;
}

// ---- Pass B: z-marching FIR conv, weights via scalar (SGPR) loads from global ----
// block = 128 threads: y = tid>>2 (32 rows), x0 = (tid&3)*8 (8 outputs in x).
// grid = (4 y-tiles, 16 z-tiles, 20 classes) = 1280 blocks.
// LDS: one z-slice, 3 fields, 38 rows x stride 44 (8 bank-groups, conflict-free).
// 7 rotating accumulator pairs (float4 lo/hi). Weight plane for aJ at phase zi: dz = 6-J.

#define F8(AL,AH,WV,q0,q1,q2,q3,q4,q5,q6,q7) { \
    AL.x=fmaf(q0,WV,AL.x); AL.y=fmaf(q1,WV,AL.y); AL.z=fmaf(q2,WV,AL.z); AL.w=fmaf(q3,WV,AL.w); \
    AH.x=fmaf(q4,WV,AH.x); AH.y=fmaf(q5,WV,AH.y); AH.z=fmaf(q6,WV,AH.z); AH.w=fmaf(q7,WV,AH.w); }

#define DZ8(AL,AH,WP) { \
    F8(AL,AH,(WP)[0], i0,i1,i2,i3,i4,i5,i6,i7) \
    F8(AL,AH,(WP)[1], i1,i2,i3,i4,i5,i6,i7,i8) \
    F8(AL,AH,(WP)[2], i2,i3,i4,i5,i6,i7,i8,i9) \
    F8(AL,AH,(WP)[3], i3,i4,i5,i6,i7,i8,i9,i10) \
    F8(AL,AH,(WP)[4], i4,i5,i6,i7,i8,i9,i10,i11) \
    F8(AL,AH,(WP)[5], i5,i6,i7,i8,i9,i10,i11,i12) \
    F8(AL,AH,(WP)[6], i6,i7,i8,i9,i10,i11,i12,i13) }

__global__ __launch_bounds__(128) void k_conv4(const float* __restrict__ masksAll,
        const float* __restrict__ mxp, const float* __restrict__ Mxp,
        const float* __restrict__ cfr, float* __restrict__ G,
        unsigned* __restrict__ keys)
{
    __shared__ __align__(16) float FL[3][38][44];
    __shared__ float r4[4];
    const int cls = blockIdx.z;
    const int y0 = blockIdx.x * 32;
    const int z0 = blockIdx.y * ZT;
    const int tid = threadIdx.x;
    const int y  = tid >> 2;          // 0..31
    const int x0 = (tid & 3) * 8;     // 0,8,16,24
    const float* mk = masksAll + (size_t)cls * VOX;
    const float* wcls = cfr + cls*1029;   // wave-uniform -> scalar loads

    float* FLf = &FL[0][0][0];
    for (int q = tid; q < 3*38*44; q += 128) FLf[q] = 0.f;

    float4 a0l{},a0h{},a1l{},a1h{},a2l{},a2h{},a3l{},a3h{},
           a4l{},a4h{},a5l{},a5h{},a6l{},a6h{};
    float hmn = 1e30f, hmx = -1e30f;

    for (int zi = z0 - 3; zi <= z0 + ZT + 2; ++zi){
        __syncthreads();
        {
            const bool zok = (unsigned)zi < (unsigned)DD;
            for (int p = tid; p < 38*44; p += 128){
                int ly = p / 44;
                int lx = p - ly*44;
                int gy = y0 + ly - 3;
                int gx = lx - 3;
                if ((unsigned)gy < (unsigned)HH && (unsigned)gx < (unsigned)WW){
                    float m = 0.f, aa = 0.f, bb = 0.f;
                    if (zok){
                        int idx = (zi*HH + gy)*WW + gx;
                        m = mk[idx]; aa = mxp[idx]; bb = Mxp[idx];
                    }
                    FL[0][ly][lx] = m*aa;
                    FL[1][ly][lx] = m*bb;
                    FL[2][ly][lx] = m;
                }
            }
        }
        __syncthreads();

        const int zo = zi - 3;
        const bool fin = (zi >= z0 + 3);
        float4 mva{}, mvb{}, mxa{}, mxb{};
        int oidx = 0;
        if (fin){                                  // prefetch finalize operands early
            oidx = (zo*HH + (y0 + y))*WW + x0;
            mva = *(const float4*)(mk  + oidx);
            mvb = *(const float4*)(mk  + oidx + 4);
            mxa = *(const float4*)(mxp + oidx);
            mxb = *(const float4*)(mxp + oidx + 4);
        }
        const int lo = z0 + 3 - zi;                // okJ: J>=lo && J-lo<ZT (wave-uniform)
        const bool ok0 = (0>=lo) && (0-lo<ZT);
        const bool ok1 = (1>=lo) && (1-lo<ZT);
        const bool ok2 = (2>=lo) && (2-lo<ZT);
        const bool ok3 = (3>=lo) && (3-lo<ZT);
        const bool ok4 = (4>=lo) && (4-lo<ZT);
        const bool ok5 = (5>=lo) && (5-lo<ZT);
        const bool ok6 = (6>=lo) && (6-lo<ZT);

        #pragma unroll
        for (int t = 0; t < 3; ++t){
            const float* fb = &FL[t][y][x0];
            const float* wt = wcls + t*343;
            #pragma unroll 1
            for (int dy = 0; dy < 7; ++dy){
                const float* fr = fb + dy*44;
                const float4 A  = *(const float4*)(fr);
                const float4 B4 = *(const float4*)(fr + 4);
                const float4 C4 = *(const float4*)(fr + 8);
                const float4 D4 = *(const float4*)(fr + 12);
                const float i0=A.x,  i1=A.y,  i2=A.z,  i3=A.w;
                const float i4=B4.x, i5=B4.y, i6=B4.z, i7=B4.w;
                const float i8=C4.x, i9=C4.y, i10=C4.z, i11=C4.w;
                const float i12=D4.x, i13=D4.y;
                const float* wd = wt + dy*7;
                if (ok6) DZ8(a6l,a6h, wd + 0)      // dz = 0
                if (ok5) DZ8(a5l,a5h, wd + 49)     // dz = 1
                if (ok4) DZ8(a4l,a4h, wd + 98)     // dz = 2
                if (ok3) DZ8(a3l,a3h, wd + 147)    // dz = 3
                if (ok2) DZ8(a2l,a2h, wd + 196)    // dz = 4
                if (ok1) DZ8(a1l,a1h, wd + 245)    // dz = 5
                if (ok0) DZ8(a0l,a0h, wd + 294)    // dz = 6
            }
        }

        if (fin){
            float4 r1, r2;
            r1.x = mva.x/(1.f + expf(-a0l.x));
            r1.y = mva.y/(1.f + expf(-a0l.y));
            r1.z = mva.z/(1.f + expf(-a0l.z));
            r1.w = mva.w/(1.f + expf(-a0l.w));
            r2.x = mvb.x/(1.f + expf(-a0h.x));
            r2.y = mvb.y/(1.f + expf(-a0h.y));
            r2.z = mvb.z/(1.f + expf(-a0h.z));
            r2.w = mvb.w/(1.f + expf(-a0h.w));
            *(float4*)(G + (size_t)cls*VOX + oidx)     = r1;
            *(float4*)(G + (size_t)cls*VOX + oidx + 4) = r2;
            float h0 = r1.x*mxa.x, h1 = r1.y*mxa.y, h2 = r1.z*mxa.z, h3 = r1.w*mxa.w;
            float h4 = r2.x*mxb.x, h5 = r2.y*mxb.y, h6 = r2.z*mxb.z, h7 = r2.w*mxb.w;
            hmn = fminf(hmn, fminf(fminf(fminf(h0,h1),fminf(h2,h3)), fminf(fminf(h4,h5),fminf(h6,h7))));
            hmx = fmaxf(hmx, fmaxf(fmaxf(fmaxf(h0,h1),fmaxf(h2,h3)), fmaxf(fmaxf(h4,h5),fmaxf(h6,h7))));
        }
        a0l=a1l; a0h=a1h; a1l=a2l; a1h=a2h; a2l=a3l; a2h=a3h;
        a3l=a4l; a3h=a4h; a4l=a5l; a4h=a5h; a5l=a6l; a5h=a6h;
        a6l = make_float4(0.f,0.f,0.f,0.f);
        a6h = make_float4(0.f,0.f,0.f,0.f);
    }

    #pragma unroll
    for (int off = 32; off > 0; off >>= 1){
        hmn = fminf(hmn, __shfl_xor(hmn, off));
        hmx = fmaxf(hmx, __shfl_xor(hmx, off));
    }
    if ((tid & 63) == 0){ r4[(tid>>6)*2] = hmn; r4[(tid>>6)*2+1] = hmx; }
    __syncthreads();
    if (tid == 0){
        atomicMin(&keys[cls],     keyOf(fminf(r4[0], r4[2])));
        atomicMax(&keys[NCL+cls], keyOf(fmaxf(r4[1], r4[3])));
    }
}

__global__ void k_thr(const unsigned* __restrict__ keys, float* __restrict__ hminA,
                      float* __restrict__ invR){
    int i = threadIdx.x;
    if (i < NCL){
        float hm = keyInv(keys[i]);
        float hM = keyInv(keys[NCL+i]);
        hminA[i] = hm;
        invR[i] = 1.f/(hM - hm);
    }
}

// ---- g = ma * (norm > 0.2), in place ----
__global__ __launch_bounds__(256) void k_region(float* G, const float* __restrict__ mx,
        const float* __restrict__ hminA, const float* __restrict__ invR)
{
    int i = blockIdx.y;
    int v = blockIdx.x*256 + threadIdx.x;
    float ma = G[i*VOX + v];
    float heat = ma * mx[v];
    float norm = (heat - hminA[i]) * invR[i];
    G[i*VOX + v] = (norm > THRESV) ? ma : 0.f;
}

// ---- per-(class,channel) sums S1 = sum x*g, S2 = sum (x*g)^2 ----
__global__ __launch_bounds__(256) void k_stats(const float* __restrict__ x,
        const float* G, float* __restrict__ part)
{
    int tid = threadIdx.x;
    int c = tid & 63, vg = tid >> 6;
    int v0 = blockIdx.x * 2048;
    float s1[NCL], s2[NCL];
    #pragma unroll
    for (int i=0;i<NCL;i++){ s1[i]=0.f; s2[i]=0.f; }
    const float* xc = x + c*VOX;
    for (int k=0;k<512;k++){
        int v = v0 + (k<<2) + vg;
        float xv = xc[v];
        #pragma unroll
        for (int i=0;i<NCL;i++){
            float p = xv * G[i*VOX + v];
            s1[i] += p;
            s2[i] = fmaf(p, p, s2[i]);
        }
    }
    __shared__ float red[4][64][2*NCL];
    #pragma unroll
    for (int i=0;i<NCL;i++){ red[vg][c][i] = s1[i]; red[vg][c][NCL+i] = s2[i]; }
    __syncthreads();
    if (vg == 0){
        float* dst = part + (size_t)blockIdx.x * (NCL*CCH*2);
        for (int i=0;i<NCL;i++){
            float a = red[0][c][i]+red[1][c][i]+red[2][c][i]+red[3][c][i];
            float b = red[0][c][NCL+i]+red[1][c][NCL+i]+red[2][c][NCL+i]+red[3][c][NCL+i];
            dst[i*CCH*2 + c*2 + 0] = a;
            dst[i*CCH*2 + c*2 + 1] = b;
        }
    }
}

// ---- finish stats: a = gamma*rinv, kc = beta - m*rinv*gamma ----
__global__ void k_params(const float* __restrict__ part, const float* __restrict__ gamma,
        const float* __restrict__ beta, float* __restrict__ aArr, float* __restrict__ kcArr)
{
    int i = blockIdx.x, c = threadIdx.x;
    float s1 = 0.f, s2 = 0.f;
    for (int b=0;b<256;b++){
        const float* p = part + (size_t)b*(NCL*CCH*2) + i*CCH*2 + c*2;
        s1 += p[0]; s2 += p[1];
    }
    float m   = s1 * (1.f/(float)VOX);
    float var = s2 * (1.f/(float)VOX) - m*m;
    float rinv = 1.f/sqrtf(var + EPSV);
    float gm = gamma[c];
    aArr[i*CCH + c]  = gm*rinv;
    kcArr[i*CCH + c] = beta[c] - m*rinv*gm;
}

__global__ void k_kcol(const float* __restrict__ kcArr, float* __restrict__ KcA){
    int c = threadIdx.x;
    if (c < CCH){
        float s = 0.f;
        for (int i=0;i<NCL;i++) s += kcArr[i*CCH + c];
        KcA[c] = s;
    }
}

// ---- final: out[c,v] = relu( x*Sum_i g_i*a_ic + K[c] ), in-place over d_out ----
__global__ __launch_bounds__(256) void k_final(const float* __restrict__ x,
        float* outAll, const float* __restrict__ aArr, const float* __restrict__ KcA)
{
    __shared__ float aL[NCL*CCH];
    __shared__ float KL[CCH];
    int tid = threadIdx.x;
    for (int q=tid; q<NCL*CCH; q+=256) aL[q] = aArr[q];
    if (tid < CCH) KL[tid] = KcA[tid];
    __syncthreads();
    int v = blockIdx.x*256 + tid;
    const float* Gp = outAll + (size_t)NCL*VOX;
    float g[NCL];
    #pragma unroll
    for (int i=0;i<NCL;i++) g[i] = Gp[i*VOX + v];
    #pragma unroll 4
    for (int c=0;c<CCH;c++){
        float P = 0.f;
        #pragma unroll
        for (int i=0;i<NCL;i++) P = fmaf(g[i], aL[i*CCH + c], P);
        float xv = x[c*VOX + v];
        outAll[c*VOX + v] = fmaxf(0.f, fmaf(xv, P, KL[c]));
    }
}

extern "C" void kernel_launch(void* const* d_in, const int* in_sizes, int n_in,
                              void* d_out, int out_size, void* d_ws, size_t ws_size,
                              hipStream_t stream)
{
    const float* x     = (const float*)d_in[0];
    const float* clsw  = (const float*)d_in[1];
    const float* clsb  = (const float*)d_in[2];
    const float* cfr   = (const float*)d_in[3];
    const float* gamma = (const float*)d_in[4];
    const float* beta  = (const float*)d_in[5];

    float* out   = (float*)d_out;
    float* logit = out + (size_t)CCH*VOX;     // second output
    float* masks = out;                       // scratch: out[0 .. 20V)
    float* G     = out + (size_t)NCL*VOX;     // scratch: out[20V .. 40V)

    float* ws    = (float*)d_ws;
    float* mxp   = ws;                        // V
    float* Mxp   = ws + VOX;                  // V
    unsigned* keys = (unsigned*)(ws + 2*(size_t)VOX);   // 40
    float* hminA = ws + 2*(size_t)VOX + 64;   // 20
    float* invR  = hminA + NCL;               // 20
    float* part  = ws + 2*(size_t)VOX + 128;  // 256*2560
    float* aArr  = part + 256*(NCL*CCH*2);    // 1280
    float* kcArr = aArr + NCL*CCH;            // 1280
    float* KcA   = kcArr + NCL*CCH;           // 64

    k_init<<<1, 64, 0, stream>>>(keys);
    k_logit_softmax<<<VOX/256, 256, 0, stream>>>(x, clsw, clsb, masks, logit, mxp, Mxp);
    k_conv4<<<dim3(4, 16, NCL), 128, 0, stream>>>(masks, mxp, Mxp, cfr, G, keys);
    k_thr<<<1, 32, 0, stream>>>(keys, hminA, invR);
    k_region<<<dim3(VOX/256, NCL), 256, 0, stream>>>(G, mxp, hminA, invR);
    k_stats<<<256, 256, 0, stream>>>(x, G, part);
    k_params<<<NCL, CCH, 0, stream>>>(part, gamma, beta, aArr, kcArr);
    k_kcol<<<1, CCH, 0, stream>>>(kcArr, KcA);
    k_final<<<VOX/256, 256, 0, stream>>>(x, out, aArr, KcA);
}